// Round 3
// baseline (5179.646 us; speedup 1.0000x reference)
//
#include <hip/hip_runtime.h>
#include <math.h>

#define S_LEN 200
#define BATCH 64
#define HID   512
#define NTAG  22
#define TCH   25              // time-chunk for gates_x staging
#define MC    (TCH*BATCH)     // 1600 rows per chunk GEMM

typedef unsigned short u16;
typedef unsigned int   u32;

__device__ __forceinline__ float bf2f(u16 u){
  union { u32 ui; float f; } v; v.ui = ((u32)u) << 16; return v.f;
}

// ---------------------------------------------------------------------------
__global__ void k_detect(const u32* __restrict__ w, int* __restrict__ flag){
  __shared__ int cnt;
  if (threadIdx.x == 0) cnt = 0;
  __syncthreads();
  int hits = 0;
  for (int i = threadIdx.x; i < 16384; i += 256){
    u32 e = (w[i] & 0x7F80u);
    if (e >= 0x3800u && e <= 0x4080u) hits++;
  }
  atomicAdd(&cnt, hits);
  __syncthreads();
  if (threadIdx.x == 0) *flag = (cnt > 8192) ? 1 : 0;
}

__global__ void k_cvt_f(const void* __restrict__ src, float* __restrict__ dst,
                        int n, const int* __restrict__ flag){
  int i = blockIdx.x*blockDim.x + threadIdx.x;
  if (i >= n) return;
  if (*flag) dst[i] = bf2f(((const u16*)src)[i]);
  else       dst[i] = ((const float*)src)[i];
}

// W_out [1024][22] -> woutT [22][1024]
__global__ void k_cvt_wt(const void* __restrict__ src, float* __restrict__ dst,
                         const int* __restrict__ flag){
  int i = blockIdx.x*blockDim.x + threadIdx.x;   // over 1024*22
  if (i >= 1024*NTAG) return;
  int k = i / NTAG, tag = i % NTAG;
  float v = (*flag) ? bf2f(((const u16*)src)[i]) : ((const float*)src)[i];
  dst[tag*1024 + k] = v;
}

__global__ void k_zero(float* __restrict__ p, int n){
  int i = blockIdx.x*blockDim.x + threadIdx.x;
  if (i < n) p[i] = 0.f;
}

// ---------------------------------------------------------------------------
// Build fwd_in/bwd_in [S][B][256] fp32.
__global__ __launch_bounds__(128)
void k_build(const int* __restrict__ ci, const int* __restrict__ lengths,
             const int* __restrict__ gid, const int* __restrict__ gm,
             const int* __restrict__ rgid, const int* __restrict__ rgm,
             const void* __restrict__ ctab, const void* __restrict__ gtab,
             const int* __restrict__ flag,
             float* __restrict__ fin, float* __restrict__ bin)
{
  int bs = blockIdx.x;              // b*S_LEN + s
  int b = bs / S_LEN, s = bs % S_LEN;
  int d = threadIdx.x;              // 0..127
  int isbf = *flag;
  int len = lengths[b];
  int sb = (s < len) ? (len - 1 - s) : s;
  size_t orow = ((size_t)s*BATCH + b)*256;

  {
    int cid = ci[bs];
    float cv = isbf ? bf2f(((const u16*)ctab)[(size_t)cid*128 + d])
                    : ((const float*)ctab)[(size_t)cid*128 + d];
    fin[orow + d] = cv;
    const int* gg = gid + (size_t)bs*8;
    const int* mm = gm  + (size_t)bs*8;
    float sum = 0.f, cntf = 0.f;
    for (int g = 0; g < 8; ++g){
      float m = (float)mm[g];
      int gw = gg[g];
      float gv = isbf ? bf2f(((const u16*)gtab)[(size_t)gw*128 + d])
                      : ((const float*)gtab)[(size_t)gw*128 + d];
      sum += m * gv; cntf += m;
    }
    fin[orow + 128 + d] = sum / fmaxf(cntf, 1.f);
  }
  {
    int bsr = b*S_LEN + sb;
    int cid = ci[bsr];
    float cv = isbf ? bf2f(((const u16*)ctab)[(size_t)cid*128 + d])
                    : ((const float*)ctab)[(size_t)cid*128 + d];
    bin[orow + d] = cv;
    const int* gg = rgid + (size_t)bsr*8;
    const int* mm = rgm  + (size_t)bsr*8;
    float sum = 0.f, cntf = 0.f;
    for (int g = 0; g < 8; ++g){
      float m = (float)mm[g];
      int gw = gg[g];
      float gv = isbf ? bf2f(((const u16*)gtab)[(size_t)gw*128 + d])
                      : ((const float*)gtab)[(size_t)gw*128 + d];
      sum += m * gv; cntf += m;
    }
    bin[orow + 128 + d] = sum / fmaxf(cntf, 1.f);
  }
}

// ---------------------------------------------------------------------------
// Chunked gates_x GEMM: C[dir][n][m] = A.W^T + bias (transposed store).
__global__ __launch_bounds__(256)
void k_gemm_ih(const float* __restrict__ Af, const float* __restrict__ Ab,
               const float* __restrict__ wih,   // [2][2048][256]
               const float* __restrict__ bias,  // [2][2048]
               float* __restrict__ gxc,         // [2][2048][MC]
               int t0)
{
  const int dir = blockIdx.z;
  const float* A = (dir ? Ab : Af) + (size_t)t0*BATCH*256;
  const float* W = wih + (size_t)dir*2048*256;
  const float* bi = bias + (size_t)dir*2048;
  float* C = gxc + (size_t)dir*2048*MC;
  const int m0 = blockIdx.y * 64;
  const int n0 = blockIdx.x * 64;
  const int tid = threadIdx.x;
  __shared__ float As[32][64];
  __shared__ float Ws[32][64];
  const int lr = tid >> 2;
  const int kq = (tid & 3) * 8;
  const int tx = tid & 15;
  const int ty = tid >> 4;
  float acc[4][4] = {};

  for (int k0 = 0; k0 < 256; k0 += 32){
    float4 a0 = *(const float4*)(A + (size_t)(m0+lr)*256 + k0 + kq);
    float4 a1 = *(const float4*)(A + (size_t)(m0+lr)*256 + k0 + kq + 4);
    float4 w0 = *(const float4*)(W + (size_t)(n0+lr)*256 + k0 + kq);
    float4 w1 = *(const float4*)(W + (size_t)(n0+lr)*256 + k0 + kq + 4);
    As[kq+0][lr]=a0.x; As[kq+1][lr]=a0.y; As[kq+2][lr]=a0.z; As[kq+3][lr]=a0.w;
    As[kq+4][lr]=a1.x; As[kq+5][lr]=a1.y; As[kq+6][lr]=a1.z; As[kq+7][lr]=a1.w;
    Ws[kq+0][lr]=w0.x; Ws[kq+1][lr]=w0.y; Ws[kq+2][lr]=w0.z; Ws[kq+3][lr]=w0.w;
    Ws[kq+4][lr]=w1.x; Ws[kq+5][lr]=w1.y; Ws[kq+6][lr]=w1.z; Ws[kq+7][lr]=w1.w;
    __syncthreads();
    #pragma unroll 8
    for (int kk = 0; kk < 32; ++kk){
      float4 av = *(const float4*)(&As[kk][ty*4]);
      float4 wv = *(const float4*)(&Ws[kk][tx*4]);
      acc[0][0]+=av.x*wv.x; acc[0][1]+=av.x*wv.y; acc[0][2]+=av.x*wv.z; acc[0][3]+=av.x*wv.w;
      acc[1][0]+=av.y*wv.x; acc[1][1]+=av.y*wv.y; acc[1][2]+=av.y*wv.z; acc[1][3]+=av.y*wv.w;
      acc[2][0]+=av.z*wv.x; acc[2][1]+=av.z*wv.y; acc[2][2]+=av.z*wv.z; acc[2][3]+=av.z*wv.w;
      acc[3][0]+=av.w*wv.x; acc[3][1]+=av.w*wv.y; acc[3][2]+=av.w*wv.z; acc[3][3]+=av.w*wv.w;
    }
    __syncthreads();
  }

  #pragma unroll
  for (int j = 0; j < 4; ++j){
    float bj = bi[n0 + tx*4 + j];
    float4 o = make_float4(acc[0][j]+bj, acc[1][j]+bj, acc[2][j]+bj, acc[3][j]+bj);
    *(float4*)(C + (size_t)(n0 + tx*4 + j)*MC + m0 + ty*4) = o;
  }
}

// ---------------------------------------------------------------------------
// LSTM step v2: 256 blocks (128 slices x 2 dir) x 512 threads (8 waves).
// Block owns 16 gate-rows = 4 gates x 4 h-rows. Wave w handles K-slice
// [w*64, w*64+64); lane = batch. Weights via wave-uniform scalar loads;
// h from global (L2/L3-hot); LDS partial-combine; 1 barrier per step.
__global__ __launch_bounds__(512)
void k_step(const float* __restrict__ whh,    // [2][2048][512]
            const float* __restrict__ gxc,    // [2][2048][MC]
            float* __restrict__ hbuf,         // [2][2][512][64]
            float* __restrict__ cbuf,         // [2][512][64]
            float* __restrict__ hseq,         // [2][200][512][64]
            int t, int tc)
{
  const int dir = blockIdx.y;
  const int hrow_base = blockIdx.x * 4;
  const int tid = threadIdx.x;
  const int b = tid & 63;
  const int w = tid >> 6;              // wave 0..7 -> k-slice
  const int k0 = w * 64;

  __shared__ float part[8*16*64];      // [w][r][b] 32 KB

  const float* hprev = hbuf + (size_t)(dir*2 + (t&1))*HID*BATCH;
  float* hnext       = hbuf + (size_t)(dir*2 + ((t+1)&1))*HID*BATCH;
  const float* whhd  = whh + (size_t)dir*2048*512;

  // load this wave's h slice into registers (coalesced, 64 x 256B)
  float hv[64];
  #pragma unroll
  for (int j = 0; j < 64; ++j)
    hv[j] = hprev[(size_t)(k0 + j)*BATCH + b];

  // 16 accumulators: r = g*4 + hr
  float acc[16];
  #pragma unroll
  for (int r = 0; r < 16; ++r) acc[r] = 0.f;

  // weight row pointers (wave-uniform -> scalar loads)
  #pragma unroll
  for (int r = 0; r < 16; ++r){
    const int row_glob = (r >> 2)*512 + hrow_base + (r & 3);
    const float* wr = whhd + (size_t)row_glob*512 + k0;
    #pragma unroll
    for (int j = 0; j < 64; ++j)
      acc[r] += wr[j] * hv[j];
  }

  #pragma unroll
  for (int r = 0; r < 16; ++r)
    part[(w*16 + r)*64 + b] = acc[r];
  __syncthreads();

  if (tid < 256){
    const int hr = tid >> 6;           // 0..3
    const int bb = tid & 63;
    const int hrow = hrow_base + hr;
    float g4[4];
    #pragma unroll
    for (int g = 0; g < 4; ++g){
      const int r = g*4 + hr;
      float s = 0.f;
      #pragma unroll
      for (int ww = 0; ww < 8; ++ww)
        s += part[(ww*16 + r)*64 + bb];
      g4[g] = s;
    }
    const float* gxb = gxc + (size_t)dir*2048*MC + (size_t)tc*BATCH + bb;
    float gi = g4[0] + gxb[(size_t)(   0 + hrow)*MC];
    float gf = g4[1] + gxb[(size_t)( 512 + hrow)*MC];
    float gg = g4[2] + gxb[(size_t)(1024 + hrow)*MC];
    float go = g4[3] + gxb[(size_t)(1536 + hrow)*MC];
    float si = 1.f/(1.f+expf(-gi));
    float sf = 1.f/(1.f+expf(-gf));
    float so = 1.f/(1.f+expf(-go));
    size_t ci_ = ((size_t)dir*HID + hrow)*BATCH + bb;
    float c = cbuf[ci_];
    c = sf*c + si*tanhf(gg);
    float h = so*tanhf(c);
    cbuf[ci_] = c;
    hnext[(size_t)hrow*BATCH + bb] = h;
    hseq[(((size_t)dir*S_LEN + t)*HID + hrow)*BATCH + bb] = h;
  }
}

// ---------------------------------------------------------------------------
// Emissions, forward part: block = t, lane = b, 4 tag-groups.
// emis[b][t][tag] = bias[tag] + sum_k hseq[0][t][k][b] * woutT[tag][k]
__global__ __launch_bounds__(256)
void k_emis_f(const float* __restrict__ hseq,
              const float* __restrict__ woutT,  // [22][1024]
              const float* __restrict__ bout,
              float* __restrict__ emis)         // [64][200][22]
{
  const int t = blockIdx.x;
  const int b = threadIdx.x & 63;
  const int tg = threadIdx.x >> 6;     // 0..3
  const float* hf = hseq + ((size_t)t*HID)*BATCH;
  float acc[6] = {0.f,0.f,0.f,0.f,0.f,0.f};
  #pragma unroll 8
  for (int k = 0; k < 512; ++k){
    float hval = hf[(size_t)k*BATCH + b];
    #pragma unroll
    for (int i = 0; i < 6; ++i){
      int tag = tg + 4*i;
      if (tag < NTAG) acc[i] += hval * woutT[tag*1024 + k];
    }
  }
  #pragma unroll
  for (int i = 0; i < 6; ++i){
    int tag = tg + 4*i;
    if (tag < NTAG)
      emis[((size_t)b*S_LEN + t)*NTAG + tag] = acc[i] + bout[tag];
  }
}

// Emissions, backward part: adds bwd-LSTM contribution at reversed position.
__global__ __launch_bounds__(256)
void k_emis_b(const float* __restrict__ hseq, const int* __restrict__ lengths,
              const float* __restrict__ woutT,
              float* __restrict__ emis)
{
  const int t = blockIdx.x;
  const int b = threadIdx.x & 63;
  const int tg = threadIdx.x >> 6;
  const int len = lengths[b];
  const int sb = (t < len) ? (len - 1 - t) : t;
  const float* hb = hseq + ((size_t)(S_LEN + t)*HID)*BATCH;
  float acc[6] = {0.f,0.f,0.f,0.f,0.f,0.f};
  #pragma unroll 8
  for (int k = 0; k < 512; ++k){
    float hval = hb[(size_t)k*BATCH + b];
    #pragma unroll
    for (int i = 0; i < 6; ++i){
      int tag = tg + 4*i;
      if (tag < NTAG) acc[i] += hval * woutT[tag*1024 + 512 + k];
    }
  }
  #pragma unroll
  for (int i = 0; i < 6; ++i){
    int tag = tg + 4*i;
    if (tag < NTAG){
      size_t idx = ((size_t)b*S_LEN + sb)*NTAG + tag;
      emis[idx] += acc[i];
    }
  }
}

// ---------------------------------------------------------------------------
__global__ __launch_bounds__(64)
void k_viterbi(const float* __restrict__ emis, const int* __restrict__ lengths,
               const float* __restrict__ trans, int* __restrict__ out)
{
  int b = blockIdx.x;
  int j = threadIdx.x;
  __shared__ float tr[NTAG*NTAG];
  __shared__ float part[NTAG];
  __shared__ unsigned char bp[(S_LEN-1)*NTAG];
  for (int i = j; i < NTAG*NTAG; i += 64) tr[i] = trans[i];
  int len = lengths[b];
  const float* eb = emis + (size_t)b*S_LEN*NTAG;
  __syncthreads();
  if (j < NTAG) part[j] = eb[j] + tr[(NTAG-2)*NTAG + j];
  __syncthreads();
  for (int t = 1; t < S_LEN; ++t){
    float best = -3.4e38f; int bi = 0;
    if (j < NTAG){
      float e = eb[t*NTAG + j];
      for (int i = 0; i < NTAG; ++i){
        float v = part[i] + tr[i*NTAG + j] + e;
        if (v > best){ best = v; bi = i; }
      }
    }
    __syncthreads();
    if (j < NTAG){
      if (t < len){ part[j] = best; bp[(t-1)*NTAG + j] = (unsigned char)bi; }
      else        { bp[(t-1)*NTAG + j] = (unsigned char)j; }
    }
    __syncthreads();
  }
  if (j == 0){
    float best = -3.4e38f; int tag = 0;
    for (int i = 0; i < NTAG; ++i){
      float v = part[i] + tr[i*NTAG + (NTAG-1)];
      if (v > best){ best = v; tag = i; }
    }
    out[b*S_LEN + S_LEN-1] = (S_LEN-1 < len) ? tag : 0;
    for (int t = S_LEN-2; t >= 0; --t){
      tag = bp[t*NTAG + tag];
      out[b*S_LEN + t] = (t < len) ? tag : 0;
    }
  }
}

// ---------------------------------------------------------------------------
extern "C" void kernel_launch(void* const* d_in, const int* in_sizes, int n_in,
                              void* d_out, int out_size, void* d_ws, size_t ws_size,
                              hipStream_t stream)
{
  (void)in_sizes; (void)n_in; (void)out_size; (void)ws_size;
  const int* char_inputs  = (const int*)d_in[0];
  const int* lengths      = (const int*)d_in[1];
  const int* gaz_ids      = (const int*)d_in[3];
  const int* gaz_mask     = (const int*)d_in[4];
  const int* rev_gaz_ids  = (const int*)d_in[5];
  const int* rev_gaz_mask = (const int*)d_in[6];
  const void* char_table  = d_in[7];
  const void* gaz_table   = d_in[8];
  const void* w_ih_f = d_in[9];
  const void* w_hh_f = d_in[10];
  const void* b_f    = d_in[11];
  const void* w_ih_b = d_in[12];
  const void* w_hh_b = d_in[13];
  const void* b_b    = d_in[14];
  const void* W_out  = d_in[15];
  const void* b_out  = d_in[16];
  const void* trans  = d_in[17];

  char* ws = (char*)d_ws;
  size_t off = 0;
  auto alloc = [&](size_t bytes)->char*{
    char* p = ws + off; off = (off + bytes + 255) & ~(size_t)255; return p;
  };
  int*   flag   = (int*)  alloc(256);
  float* whh32  = (float*)alloc(2ull*2048*512*4);   //  8.4 MB
  float* wih32  = (float*)alloc(2ull*2048*256*4);   //  4.2 MB
  float* bias32 = (float*)alloc(2ull*2048*4);
  float* woutT  = (float*)alloc(22ull*1024*4);
  float* bout32 = (float*)alloc(22ull*4);
  float* trans32= (float*)alloc(484ull*4);
  float* fwd_in = (float*)alloc(12800ull*256*4);    // 13.1 MB
  float* bwd_in = (float*)alloc(12800ull*256*4);    // 13.1 MB
  float* gxc    = (float*)alloc(2ull*2048*MC*4);    // 26.2 MB
  float* hbuf   = (float*)alloc(2ull*2*512*64*4);
  float* cbuf   = (float*)alloc(2ull*512*64*4);
  float* hseq   = (float*)alloc(2ull*200*512*64*4); // 52.4 MB
  float* emis   = (float*)alloc(12800ull*22*4);

  k_detect<<<1,256,0,stream>>>((const u32*)char_table, flag);
  k_cvt_f<<<4096,256,0,stream>>>(w_hh_f, whh32,           1048576, flag);
  k_cvt_f<<<4096,256,0,stream>>>(w_hh_b, whh32 + 1048576, 1048576, flag);
  k_cvt_f<<<2048,256,0,stream>>>(w_ih_f, wih32,            524288, flag);
  k_cvt_f<<<2048,256,0,stream>>>(w_ih_b, wih32 + 524288,   524288, flag);
  k_cvt_f<<<8,256,0,stream>>>(b_f, bias32,        2048, flag);
  k_cvt_f<<<8,256,0,stream>>>(b_b, bias32 + 2048, 2048, flag);
  k_cvt_wt<<<88,256,0,stream>>>(W_out, woutT, flag);
  k_cvt_f<<<1,256,0,stream>>>(b_out, bout32, 22, flag);
  k_cvt_f<<<2,256,0,stream>>>(trans, trans32, 484, flag);

  k_build<<<12800,128,0,stream>>>(char_inputs, lengths, gaz_ids, gaz_mask,
                                  rev_gaz_ids, rev_gaz_mask, char_table, gaz_table,
                                  flag, fwd_in, bwd_in);

  k_zero<<<768,256,0,stream>>>(hbuf, 2*2*512*64 + 2*512*64);

  for (int t0 = 0; t0 < S_LEN; t0 += TCH){
    k_gemm_ih<<<dim3(32,TCH,2),256,0,stream>>>(fwd_in, bwd_in, wih32, bias32,
                                               gxc, t0);
    for (int tc = 0; tc < TCH; ++tc)
      k_step<<<dim3(128,2),512,0,stream>>>(whh32, gxc, hbuf, cbuf, hseq, t0+tc, tc);
  }

  k_emis_f<<<S_LEN,256,0,stream>>>(hseq, woutT, bout32, emis);
  k_emis_b<<<S_LEN,256,0,stream>>>(hseq, lengths, woutT, emis);
  k_viterbi<<<64,64,0,stream>>>(emis, lengths, trans32, (int*)d_out);
}

// Round 4
// 2811.998 us; speedup vs baseline: 1.8420x; 1.8420x over previous
//
#include <hip/hip_runtime.h>
#include <math.h>

#define S_LEN 200
#define BATCH 64
#define HID   512
#define NTAG  22
#define TCH   25              // time-chunk for gates_x staging
#define MC    (TCH*BATCH)     // 1600 rows per chunk GEMM

typedef unsigned short u16;
typedef unsigned int   u32;

__device__ __forceinline__ float bf2f(u16 u){
  union { u32 ui; float f; } v; v.ui = ((u32)u) << 16; return v.f;
}

// ---------------------------------------------------------------------------
__global__ void k_detect(const u32* __restrict__ w, int* __restrict__ flag){
  __shared__ int cnt;
  if (threadIdx.x == 0) cnt = 0;
  __syncthreads();
  int hits = 0;
  for (int i = threadIdx.x; i < 16384; i += 256){
    u32 e = (w[i] & 0x7F80u);
    if (e >= 0x3800u && e <= 0x4080u) hits++;
  }
  atomicAdd(&cnt, hits);
  __syncthreads();
  if (threadIdx.x == 0) *flag = (cnt > 8192) ? 1 : 0;
}

__global__ void k_cvt_f(const void* __restrict__ src, float* __restrict__ dst,
                        int n, const int* __restrict__ flag){
  int i = blockIdx.x*blockDim.x + threadIdx.x;
  if (i >= n) return;
  if (*flag) dst[i] = bf2f(((const u16*)src)[i]);
  else       dst[i] = ((const float*)src)[i];
}

// W_out [1024][22] -> wpad [2][512][24]  (tag-padded, k-major per half)
__global__ void k_cvt_wt(const void* __restrict__ src, float* __restrict__ dst,
                         const int* __restrict__ flag){
  int i = blockIdx.x*blockDim.x + threadIdx.x;   // over 1024*24
  if (i >= 1024*24) return;
  int k = i / 24, tag = i % 24;
  float v = 0.f;
  if (tag < NTAG){
    v = (*flag) ? bf2f(((const u16*)src)[k*NTAG + tag])
                : ((const float*)src)[k*NTAG + tag];
  }
  int half = k >> 9, kk = k & 511;
  dst[((size_t)half*512 + kk)*24 + tag] = v;
}

__global__ void k_zero(float* __restrict__ p, int n){
  int i = blockIdx.x*blockDim.x + threadIdx.x;
  if (i < n) p[i] = 0.f;
}

// ---------------------------------------------------------------------------
// Build fwd_in/bwd_in [S][B][256] fp32.
__global__ __launch_bounds__(128)
void k_build(const int* __restrict__ ci, const int* __restrict__ lengths,
             const int* __restrict__ gid, const int* __restrict__ gm,
             const int* __restrict__ rgid, const int* __restrict__ rgm,
             const void* __restrict__ ctab, const void* __restrict__ gtab,
             const int* __restrict__ flag,
             float* __restrict__ fin, float* __restrict__ bin)
{
  int bs = blockIdx.x;              // b*S_LEN + s
  int b = bs / S_LEN, s = bs % S_LEN;
  int d = threadIdx.x;              // 0..127
  int isbf = *flag;
  int len = lengths[b];
  int sb = (s < len) ? (len - 1 - s) : s;
  size_t orow = ((size_t)s*BATCH + b)*256;

  {
    int cid = ci[bs];
    float cv = isbf ? bf2f(((const u16*)ctab)[(size_t)cid*128 + d])
                    : ((const float*)ctab)[(size_t)cid*128 + d];
    fin[orow + d] = cv;
    const int* gg = gid + (size_t)bs*8;
    const int* mm = gm  + (size_t)bs*8;
    float sum = 0.f, cntf = 0.f;
    for (int g = 0; g < 8; ++g){
      float m = (float)mm[g];
      int gw = gg[g];
      float gv = isbf ? bf2f(((const u16*)gtab)[(size_t)gw*128 + d])
                      : ((const float*)gtab)[(size_t)gw*128 + d];
      sum += m * gv; cntf += m;
    }
    fin[orow + 128 + d] = sum / fmaxf(cntf, 1.f);
  }
  {
    int bsr = b*S_LEN + sb;
    int cid = ci[bsr];
    float cv = isbf ? bf2f(((const u16*)ctab)[(size_t)cid*128 + d])
                    : ((const float*)ctab)[(size_t)cid*128 + d];
    bin[orow + d] = cv;
    const int* gg = rgid + (size_t)bsr*8;
    const int* mm = rgm  + (size_t)bsr*8;
    float sum = 0.f, cntf = 0.f;
    for (int g = 0; g < 8; ++g){
      float m = (float)mm[g];
      int gw = gg[g];
      float gv = isbf ? bf2f(((const u16*)gtab)[(size_t)gw*128 + d])
                      : ((const float*)gtab)[(size_t)gw*128 + d];
      sum += m * gv; cntf += m;
    }
    bin[orow + 128 + d] = sum / fmaxf(cntf, 1.f);
  }
}

// ---------------------------------------------------------------------------
// Chunked gates_x GEMM: C[dir][n][m] = A.W^T + bias (transposed store).
__global__ __launch_bounds__(256)
void k_gemm_ih(const float* __restrict__ Af, const float* __restrict__ Ab,
               const float* __restrict__ wih,   // [2][2048][256]
               const float* __restrict__ bias,  // [2][2048]
               float* __restrict__ gxc,         // [2][2048][MC]
               int t0)
{
  const int dir = blockIdx.z;
  const float* A = (dir ? Ab : Af) + (size_t)t0*BATCH*256;
  const float* W = wih + (size_t)dir*2048*256;
  const float* bi = bias + (size_t)dir*2048;
  float* C = gxc + (size_t)dir*2048*MC;
  const int m0 = blockIdx.y * 64;
  const int n0 = blockIdx.x * 64;
  const int tid = threadIdx.x;
  __shared__ float As[32][64];
  __shared__ float Ws[32][64];
  const int lr = tid >> 2;
  const int kq = (tid & 3) * 8;
  const int tx = tid & 15;
  const int ty = tid >> 4;
  float acc[4][4] = {};

  for (int k0 = 0; k0 < 256; k0 += 32){
    float4 a0 = *(const float4*)(A + (size_t)(m0+lr)*256 + k0 + kq);
    float4 a1 = *(const float4*)(A + (size_t)(m0+lr)*256 + k0 + kq + 4);
    float4 w0 = *(const float4*)(W + (size_t)(n0+lr)*256 + k0 + kq);
    float4 w1 = *(const float4*)(W + (size_t)(n0+lr)*256 + k0 + kq + 4);
    As[kq+0][lr]=a0.x; As[kq+1][lr]=a0.y; As[kq+2][lr]=a0.z; As[kq+3][lr]=a0.w;
    As[kq+4][lr]=a1.x; As[kq+5][lr]=a1.y; As[kq+6][lr]=a1.z; As[kq+7][lr]=a1.w;
    Ws[kq+0][lr]=w0.x; Ws[kq+1][lr]=w0.y; Ws[kq+2][lr]=w0.z; Ws[kq+3][lr]=w0.w;
    Ws[kq+4][lr]=w1.x; Ws[kq+5][lr]=w1.y; Ws[kq+6][lr]=w1.z; Ws[kq+7][lr]=w1.w;
    __syncthreads();
    #pragma unroll 8
    for (int kk = 0; kk < 32; ++kk){
      float4 av = *(const float4*)(&As[kk][ty*4]);
      float4 wv = *(const float4*)(&Ws[kk][tx*4]);
      acc[0][0]+=av.x*wv.x; acc[0][1]+=av.x*wv.y; acc[0][2]+=av.x*wv.z; acc[0][3]+=av.x*wv.w;
      acc[1][0]+=av.y*wv.x; acc[1][1]+=av.y*wv.y; acc[1][2]+=av.y*wv.z; acc[1][3]+=av.y*wv.w;
      acc[2][0]+=av.z*wv.x; acc[2][1]+=av.z*wv.y; acc[2][2]+=av.z*wv.z; acc[2][3]+=av.z*wv.w;
      acc[3][0]+=av.w*wv.x; acc[3][1]+=av.w*wv.y; acc[3][2]+=av.w*wv.z; acc[3][3]+=av.w*wv.w;
    }
    __syncthreads();
  }

  #pragma unroll
  for (int j = 0; j < 4; ++j){
    float bj = bi[n0 + tx*4 + j];
    float4 o = make_float4(acc[0][j]+bj, acc[1][j]+bj, acc[2][j]+bj, acc[3][j]+bj);
    *(float4*)(C + (size_t)(n0 + tx*4 + j)*MC + m0 + ty*4) = o;
  }
}

// ---------------------------------------------------------------------------
// LSTM step v3: 256 blocks (128 slices x 2 dir) x 512 threads (8 waves).
// Wave w owns K-slice [w*64, w*64+64); lane = batch. Weight addresses are
// FORCED wave-uniform via readfirstlane so the compiler emits s_load
// (scalar) weight fetches; h comes as coalesced vector loads.
__global__ __launch_bounds__(512)
void k_step(const float* __restrict__ whh,    // [2][2048][512]
            const float* __restrict__ gxc,    // [2][2048][MC]
            float* __restrict__ hbuf,         // [2][2][512][64]
            float* __restrict__ cbuf,         // [2][512][64]
            float* __restrict__ hseq,         // [2][200][512][64]
            int t, int tc)
{
  const int dir = blockIdx.y;
  const int hrow_base = blockIdx.x * 4;
  const int tid = threadIdx.x;
  const int b = tid & 63;
  const int uw = __builtin_amdgcn_readfirstlane(tid >> 6);  // wave id 0..7
  const int uk0 = uw * 64;                                  // scalar K-offset

  __shared__ float part[8*16*64];      // [w][r][b] 32 KB

  const float* hprev = hbuf + (size_t)(dir*2 + (t&1))*HID*BATCH;
  float* hnext       = hbuf + (size_t)(dir*2 + ((t+1)&1))*HID*BATCH;
  const float* whhd  = whh + (size_t)dir*2048*512;

  // this wave's h slice -> registers (coalesced vector loads)
  float hv[64];
  #pragma unroll
  for (int j = 0; j < 64; ++j)
    hv[j] = hprev[(size_t)(uk0 + j)*BATCH + b];

  float acc[16];
  #pragma unroll
  for (int r = 0; r < 16; ++r) acc[r] = 0.f;

  #pragma unroll
  for (int r = 0; r < 16; ++r){
    const int row_glob = (r >> 2)*512 + hrow_base + (r & 3);
    const float* wr = whhd + (size_t)row_glob*512 + uk0;   // wave-uniform
    #pragma unroll
    for (int j = 0; j < 64; ++j)
      acc[r] += wr[j] * hv[j];
  }

  #pragma unroll
  for (int r = 0; r < 16; ++r)
    part[(uw*16 + r)*64 + b] = acc[r];
  __syncthreads();

  if (tid < 256){
    const int hr = tid >> 6;           // 0..3
    const int bb = tid & 63;
    const int hrow = hrow_base + hr;
    float g4[4];
    #pragma unroll
    for (int g = 0; g < 4; ++g){
      const int r = g*4 + hr;
      float s = 0.f;
      #pragma unroll
      for (int ww = 0; ww < 8; ++ww)
        s += part[(ww*16 + r)*64 + bb];
      g4[g] = s;
    }
    const float* gxb = gxc + (size_t)dir*2048*MC + (size_t)tc*BATCH + bb;
    float gi = g4[0] + gxb[(size_t)(   0 + hrow)*MC];
    float gf = g4[1] + gxb[(size_t)( 512 + hrow)*MC];
    float gg = g4[2] + gxb[(size_t)(1024 + hrow)*MC];
    float go = g4[3] + gxb[(size_t)(1536 + hrow)*MC];
    float si = 1.f/(1.f+expf(-gi));
    float sf = 1.f/(1.f+expf(-gf));
    float so = 1.f/(1.f+expf(-go));
    size_t ci_ = ((size_t)dir*HID + hrow)*BATCH + bb;
    float c = cbuf[ci_];
    c = sf*c + si*tanhf(gg);
    float h = so*tanhf(c);
    cbuf[ci_] = c;
    hnext[(size_t)hrow*BATCH + bb] = h;
    hseq[(((size_t)dir*S_LEN + t)*HID + hrow)*BATCH + bb] = h;
  }
}

// ---------------------------------------------------------------------------
// Emissions: grid (S_LEN, 2), 256 threads. h staged through LDS in 16 KB
// chunks (coalesced float4); weights via wave-uniform scalar loads from the
// padded [2][512][24] table. dir=0 -> emisF[b][t][22] (+bias);
// dir=1 -> emisB[b][rev(t)][22] (bijective scatter, no race).
__global__ __launch_bounds__(256)
void k_emis(const float* __restrict__ hseq, const int* __restrict__ lengths,
            const float* __restrict__ wpad,   // [2][512][24]
            const float* __restrict__ bout,   // [22]
            float* __restrict__ emisF, float* __restrict__ emisB)
{
  const int t = blockIdx.x;
  const int dir = blockIdx.y;
  const int tid = threadIdx.x;
  const int b = tid & 63;
  const int utg = __builtin_amdgcn_readfirstlane(tid >> 6);  // 0..3

  __shared__ float hl[64*64];          // 16 KB: 64 k-rows x 64 batches

  const float* hsrc = hseq + ((size_t)(dir*S_LEN + t)*HID)*BATCH;
  const float* wbase = wpad + (size_t)dir*512*24 + utg*6;

  float acc[6] = {0.f,0.f,0.f,0.f,0.f,0.f};

  for (int c = 0; c < 8; ++c){
    const float4* s4 = (const float4*)(hsrc + (size_t)c*64*64);
    float4* d4 = (float4*)hl;
    #pragma unroll
    for (int q = 0; q < 4; ++q) d4[q*256 + tid] = s4[q*256 + tid];
    __syncthreads();
    const float* wrow = wbase + (size_t)c*64*24;
    #pragma unroll 4
    for (int k = 0; k < 64; ++k){
      float hval = hl[k*64 + b];
      #pragma unroll
      for (int i = 0; i < 6; ++i) acc[i] += hval * wrow[k*24 + i];
    }
    __syncthreads();
  }

  const int len = lengths[b];
  const int pos = dir ? ((t < len) ? (len - 1 - t) : t) : t;
  float* dst = (dir ? emisB : emisF) + ((size_t)b*S_LEN + pos)*NTAG;
  #pragma unroll
  for (int i = 0; i < 6; ++i){
    int tag = utg*6 + i;
    if (tag < NTAG) dst[tag] = acc[i] + (dir ? 0.f : bout[tag]);
  }
}

// ---------------------------------------------------------------------------
__global__ __launch_bounds__(64)
void k_viterbi(const float* __restrict__ emisF, const float* __restrict__ emisB,
               const int* __restrict__ lengths,
               const float* __restrict__ trans, int* __restrict__ out)
{
  int b = blockIdx.x;
  int j = threadIdx.x;
  __shared__ float tr[NTAG*NTAG];
  __shared__ float part[NTAG];
  __shared__ unsigned char bp[(S_LEN-1)*NTAG];
  for (int i = j; i < NTAG*NTAG; i += 64) tr[i] = trans[i];
  int len = lengths[b];
  const float* ef = emisF + (size_t)b*S_LEN*NTAG;
  const float* eb = emisB + (size_t)b*S_LEN*NTAG;
  __syncthreads();
  if (j < NTAG) part[j] = ef[j] + eb[j] + tr[(NTAG-2)*NTAG + j];
  __syncthreads();
  for (int t = 1; t < S_LEN; ++t){
    float best = -3.4e38f; int bi = 0;
    if (j < NTAG){
      float e = ef[t*NTAG + j] + eb[t*NTAG + j];
      for (int i = 0; i < NTAG; ++i){
        float v = part[i] + tr[i*NTAG + j] + e;
        if (v > best){ best = v; bi = i; }
      }
    }
    __syncthreads();
    if (j < NTAG){
      if (t < len){ part[j] = best; bp[(t-1)*NTAG + j] = (unsigned char)bi; }
      else        { bp[(t-1)*NTAG + j] = (unsigned char)j; }
    }
    __syncthreads();
  }
  if (j == 0){
    float best = -3.4e38f; int tag = 0;
    for (int i = 0; i < NTAG; ++i){
      float v = part[i] + tr[i*NTAG + (NTAG-1)];
      if (v > best){ best = v; tag = i; }
    }
    out[b*S_LEN + S_LEN-1] = (S_LEN-1 < len) ? tag : 0;
    for (int t = S_LEN-2; t >= 0; --t){
      tag = bp[t*NTAG + tag];
      out[b*S_LEN + t] = (t < len) ? tag : 0;
    }
  }
}

// ---------------------------------------------------------------------------
extern "C" void kernel_launch(void* const* d_in, const int* in_sizes, int n_in,
                              void* d_out, int out_size, void* d_ws, size_t ws_size,
                              hipStream_t stream)
{
  (void)in_sizes; (void)n_in; (void)out_size; (void)ws_size;
  const int* char_inputs  = (const int*)d_in[0];
  const int* lengths      = (const int*)d_in[1];
  const int* gaz_ids      = (const int*)d_in[3];
  const int* gaz_mask     = (const int*)d_in[4];
  const int* rev_gaz_ids  = (const int*)d_in[5];
  const int* rev_gaz_mask = (const int*)d_in[6];
  const void* char_table  = d_in[7];
  const void* gaz_table   = d_in[8];
  const void* w_ih_f = d_in[9];
  const void* w_hh_f = d_in[10];
  const void* b_f    = d_in[11];
  const void* w_ih_b = d_in[12];
  const void* w_hh_b = d_in[13];
  const void* b_b    = d_in[14];
  const void* W_out  = d_in[15];
  const void* b_out  = d_in[16];
  const void* trans  = d_in[17];

  char* ws = (char*)d_ws;
  size_t off = 0;
  auto alloc = [&](size_t bytes)->char*{
    char* p = ws + off; off = (off + bytes + 255) & ~(size_t)255; return p;
  };
  int*   flag   = (int*)  alloc(256);
  float* whh32  = (float*)alloc(2ull*2048*512*4);   //  8.4 MB
  float* wih32  = (float*)alloc(2ull*2048*256*4);   //  4.2 MB
  float* bias32 = (float*)alloc(2ull*2048*4);
  float* wpad   = (float*)alloc(2ull*512*24*4);
  float* bout32 = (float*)alloc(22ull*4);
  float* trans32= (float*)alloc(484ull*4);
  float* fwd_in = (float*)alloc(12800ull*256*4);    // 13.1 MB
  float* bwd_in = (float*)alloc(12800ull*256*4);    // 13.1 MB
  float* gxc    = (float*)alloc(2ull*2048*MC*4);    // 26.2 MB
  float* hbuf   = (float*)alloc(2ull*2*512*64*4);
  float* cbuf   = (float*)alloc(2ull*512*64*4);
  float* hseq   = (float*)alloc(2ull*200*512*64*4); // 52.4 MB
  float* emisF  = (float*)alloc(12800ull*22*4);
  float* emisB  = (float*)alloc(12800ull*22*4);

  k_detect<<<1,256,0,stream>>>((const u32*)char_table, flag);
  k_cvt_f<<<4096,256,0,stream>>>(w_hh_f, whh32,           1048576, flag);
  k_cvt_f<<<4096,256,0,stream>>>(w_hh_b, whh32 + 1048576, 1048576, flag);
  k_cvt_f<<<2048,256,0,stream>>>(w_ih_f, wih32,            524288, flag);
  k_cvt_f<<<2048,256,0,stream>>>(w_ih_b, wih32 + 524288,   524288, flag);
  k_cvt_f<<<8,256,0,stream>>>(b_f, bias32,        2048, flag);
  k_cvt_f<<<8,256,0,stream>>>(b_b, bias32 + 2048, 2048, flag);
  k_cvt_wt<<<96,256,0,stream>>>(W_out, wpad, flag);
  k_cvt_f<<<1,256,0,stream>>>(b_out, bout32, 22, flag);
  k_cvt_f<<<2,256,0,stream>>>(trans, trans32, 484, flag);

  k_build<<<12800,128,0,stream>>>(char_inputs, lengths, gaz_ids, gaz_mask,
                                  rev_gaz_ids, rev_gaz_mask, char_table, gaz_table,
                                  flag, fwd_in, bwd_in);

  k_zero<<<768,256,0,stream>>>(hbuf, 2*2*512*64 + 2*512*64);

  for (int t0 = 0; t0 < S_LEN; t0 += TCH){
    k_gemm_ih<<<dim3(32,TCH,2),256,0,stream>>>(fwd_in, bwd_in, wih32, bias32,
                                               gxc, t0);
    for (int tc = 0; tc < TCH; ++tc)
      k_step<<<dim3(128,2),512,0,stream>>>(whh32, gxc, hbuf, cbuf, hseq, t0+tc, tc);
  }

  k_emis<<<dim3(S_LEN,2),256,0,stream>>>(hseq, lengths, wpad, bout32, emisF, emisB);
  k_viterbi<<<64,64,0,stream>>>(emisF, emisB, lengths, trans32, (int*)d_out);
}